// Round 10
// baseline (569.490 us; speedup 1.0000x reference)
//
#include <hip/hip_runtime.h>

#define N_USERS 200000
#define N_ITEMS 100000
#define N_NODES 300000
#define EMB     64
#define N_EDGES 5000000

typedef float f32x4 __attribute__((ext_vector_type(4)));
typedef _Float16 f16;
typedef f16 f16x4 __attribute__((ext_vector_type(4)));     // 8 B gather granule

// 8 B staged record: rc = (rowLow8 << 19) | col  (col < 2^19)
struct alignas(8) SRec { unsigned int rc; float val; };

#define BSHIFT 8
#define BROWS  (1 << BSHIFT)                               // 256
#define NBUCK  ((N_NODES + BROWS - 1) >> BSHIFT)           // 1172
#define CAP    5120                                        // mean 4267 (+13 sigma)
#define BIN_CHUNK 16384                                    // edges per bin block (2-pass)
#define COLMASK 0x7FFFFu
#define INIT_BLOCKS 2048                                   // grid-strided init part

// ---------------------------------------------------------------------------
// Fused init + bin (R8 batched loads; BSHIFT 8 spreads the 16K LDS hist
// atomics over 1172 slots instead of 293 -> same-address contention /4).
// ---------------------------------------------------------------------------
__global__ __launch_bounds__(256) void fused_init_bin_kernel(
    const float* __restrict__ user, const float* __restrict__ item,
    f16* __restrict__ x0,
    const int4* __restrict__ row4, const int4* __restrict__ col4,
    const float4* __restrict__ val4,
    int* __restrict__ bcursor, SRec* __restrict__ stage, int bin_blocks)
{
    int t = threadIdx.x;
    if ((int)blockIdx.x < bin_blocks) {
        __shared__ int hist[NBUCK];
        __shared__ int base_[NBUCK];
        const int Q = N_EDGES / 4;                    // int4 count (N_EDGES%4==0)
        long q0 = (long)blockIdx.x * (BIN_CHUNK / 4); // 4096 int4 / block

        for (int k = t; k < NBUCK; k += 256) hist[k] = 0;
        __syncthreads();

        // ---- pass A: batch row loads, then count 16K edges ----
        int4 ra[16];
        const bool full = (q0 + (BIN_CHUNK / 4) <= Q);
        if (full) {
            #pragma unroll
            for (int k = 0; k < 16; ++k)
                ra[k] = row4[q0 + k * 256 + t];
            #pragma unroll
            for (int k = 0; k < 16; ++k) {
                atomicAdd(&hist[ra[k].x >> BSHIFT], 1);
                atomicAdd(&hist[ra[k].y >> BSHIFT], 1);
                atomicAdd(&hist[ra[k].z >> BSHIFT], 1);
                atomicAdd(&hist[ra[k].w >> BSHIFT], 1);
            }
        } else {
            #pragma unroll
            for (int k = 0; k < 16; ++k) {
                long q = q0 + k * 256 + t;
                if (q < Q) {
                    ra[k] = row4[q];
                    atomicAdd(&hist[ra[k].x >> BSHIFT], 1);
                    atomicAdd(&hist[ra[k].y >> BSHIFT], 1);
                    atomicAdd(&hist[ra[k].z >> BSHIFT], 1);
                    atomicAdd(&hist[ra[k].w >> BSHIFT], 1);
                }
            }
        }
        __syncthreads();
        // one claim per bucket for the whole 16K chunk -> dense runs
        for (int k = t; k < NBUCK; k += 256) {
            int h = hist[k];
            base_[k] = h ? atomicAdd(&bcursor[k], h) : 0;
            hist[k] = 0;                               // reuse as local cursor
        }
        __syncthreads();
        // ---- pass B: col/val batched x4, rows from registers ----
        #pragma unroll
        for (int g = 0; g < 4; ++g) {
            int4 c4[4]; float4 v4[4];
            #pragma unroll
            for (int j = 0; j < 4; ++j) {
                long q = q0 + (g * 4 + j) * 256 + t;
                if (q < Q) { c4[j] = col4[q]; v4[j] = val4[q]; }
            }
            #pragma unroll
            for (int j = 0; j < 4; ++j) {
                long q = q0 + (g * 4 + j) * 256 + t;
                if (q < Q) {
                    int4 r = ra[g * 4 + j];
                    int   rr[4] = {r.x, r.y, r.z, r.w};
                    int   cc[4] = {c4[j].x, c4[j].y, c4[j].z, c4[j].w};
                    float vv[4] = {v4[j].x, v4[j].y, v4[j].z, v4[j].w};
                    #pragma unroll
                    for (int m = 0; m < 4; ++m) {
                        int b   = rr[m] >> BSHIFT;
                        int pos = base_[b] + atomicAdd(&hist[b], 1);
                        SRec s;
                        s.rc  = ((unsigned)(rr[m] & (BROWS - 1)) << 19)
                              | (unsigned)cc[m];
                        s.val = vv[m];
                        stage[(size_t)b * CAP + pos] = s;
                    }
                }
            }
        }
    } else {
        const int nu4 = N_USERS * EMB / 4;
        const int nt4 = N_NODES * EMB / 4;
        int i0 = ((int)blockIdx.x - bin_blocks) * 256 + t;
        const int stride = INIT_BLOCKS * 256;
        for (int i = i0; i < nt4; i += stride) {
            float4 vv = (i < nu4) ? reinterpret_cast<const float4*>(user)[i]
                                  : reinterpret_cast<const float4*>(item)[i - nu4];
            f16x4 hx = {(f16)vv.x, (f16)vv.y, (f16)vv.z, (f16)vv.w};
            reinterpret_cast<f16x4*>(x0)[i] = hx;
        }
    }
}

// ---------------------------------------------------------------------------
// Per-bucket (256 rows): count -> 256-wide scan -> LDS row-sort -> dense
// stream-out to BUCKET-STRIDED packed (pos = b*CAP + local). No inter-bucket
// prefix (start[] carries strided offsets; cnt16[] carries row degrees).
// R9 fix targets: 1172 blocks @ ~5/CU = single round (was 293 @ 1/CU = 1.14
// rounds -> 37-block tail at 14% CU util), serial 293-iter prefix eliminated.
// ---------------------------------------------------------------------------
__global__ __launch_bounds__(256) void bucket_scan_scatter_kernel(
    const SRec* __restrict__ stage, const int* __restrict__ bsize,
    int* __restrict__ start, unsigned short* __restrict__ cnt16,
    int* __restrict__ pcol, f16* __restrict__ pval)
{
    __shared__ int cur[BROWS];          // 256: counts -> cursors
    __shared__ int sc[256];
    __shared__ int lcol[CAP];           // 20 KB
    __shared__ f16 lval[CAP];           // 10 KB

    int b    = blockIdx.x;
    int t    = threadIdx.x;
    int row0 = b << BSHIFT;
    int rows = N_NODES - row0; if (rows > BROWS) rows = BROWS;

    const int  size = bsize[b];
    const int  base = b * CAP;
    const SRec* seg = stage + (size_t)b * CAP;

    cur[t] = 0;
    __syncthreads();

    // pass A: per-row counts
    for (int e = t; e < size; e += 256)
        atomicAdd(&cur[seg[e].rc >> 19], 1);
    __syncthreads();

    // exclusive scan over 256 counts
    int a = cur[t];
    sc[t] = a;
    __syncthreads();
    for (int ofs = 1; ofs < 256; ofs <<= 1) {
        int v = (t >= ofs) ? sc[t - ofs] : 0;
        __syncthreads();
        sc[t] += v;
        __syncthreads();
    }
    int excl = sc[t] - a;
    cur[t] = excl;                      // local cursor
    if (t < rows) {
        start[row0 + t] = base + excl;  // strided global offset
        cnt16[row0 + t] = (unsigned short)a;
    }
    __syncthreads();

    // pass B: row-sort into LDS (seg L2-warm from pass A)
    for (int e = t; e < size; e += 256) {
        SRec srec = seg[e];
        int idx = atomicAdd(&cur[srec.rc >> 19], 1);
        lcol[idx] = (int)(srec.rc & COLMASK);
        lval[idx] = (f16)srec.val;
    }
    __syncthreads();

    // stream out: dense, coalesced, payload-only
    for (int i = t; i < size; i += 256) pcol[base + i] = lcol[i];
    for (int i = t; i < size; i += 256) pval[base + i] = lval[i];
}

// ---------------------------------------------------------------------------
// CSR SpMM over fp16 tables (strided CSR: beg = start[g], end = beg+cnt16[g]).
// mode 0: write y only. mode 1 (layer 2): out = 0.25*(x0+x1+x2+acc).
// Established floor: compulsory miss-path bytes (8 XCD x table + packed) at
// ~3.9 TB/s pattern rate; L2 already captures all gather reuse (52% hit).
// ---------------------------------------------------------------------------
__global__ __launch_bounds__(256, 4) void spmm_csr_kernel(
    const f16* __restrict__ x, const int* __restrict__ pcol,
    const f16* __restrict__ pval, const int* __restrict__ start,
    const unsigned short* __restrict__ cnt16,
    f16* __restrict__ y,
    const f16* __restrict__ xa, const f16* __restrict__ xb,
    float* __restrict__ out, int mode)
{
    int g = blockIdx.x * (256 / 16) + (threadIdx.x >> 4);
    if (g >= N_NODES) return;
    const int lane16 = threadIdx.x & 15;
    const int d      = lane16 * 4;
    const int gbase  = threadIdx.x & 48;

    int beg = start[g];
    int end = beg + cnt16[g];
    float4 acc = {0.f, 0.f, 0.f, 0.f};

    for (int jb = beg; jb < end; jb += 16) {
        int   mycol = 0; float myval = 0.f;
        if (jb + lane16 < end) {
            mycol = pcol[jb + lane16];
            myval = (float)pval[jb + lane16];
        }

        int   cols[16];
        float vals[16];
        #pragma unroll
        for (int k = 0; k < 16; ++k) {
            cols[k] = __shfl(mycol, gbase + k, 64);
            vals[k] = __shfl(myval, gbase + k, 64);
        }

        f16x4 xv[16];
        #pragma unroll
        for (int k = 0; k < 16; ++k) {
            xv[k] = *reinterpret_cast<const f16x4*>(
                x + (size_t)cols[k] * EMB + d);
        }

        #pragma unroll
        for (int k = 0; k < 16; ++k) {
            acc.x += vals[k] * (float)xv[k].x;
            acc.y += vals[k] * (float)xv[k].y;
            acc.z += vals[k] * (float)xv[k].z;
            acc.w += vals[k] * (float)xv[k].w;
        }
    }

    const size_t rofs = (size_t)g * EMB + d;
    if (mode == 0) {
        f16x4 hy = {(f16)acc.x, (f16)acc.y, (f16)acc.z, (f16)acc.w};
        *reinterpret_cast<f16x4*>(y + rofs) = hy;
    } else {
        f16x4 v0 = *reinterpret_cast<const f16x4*>(xa + rofs);
        f16x4 v1 = *reinterpret_cast<const f16x4*>(xb + rofs);
        f16x4 v2 = *reinterpret_cast<const f16x4*>(x  + rofs);
        f32x4 o;
        o.x = 0.25f * ((float)v0.x + (float)v1.x + (float)v2.x + acc.x);
        o.y = 0.25f * ((float)v0.y + (float)v1.y + (float)v2.y + acc.y);
        o.z = 0.25f * ((float)v0.z + (float)v1.z + (float)v2.z + acc.z);
        o.w = 0.25f * ((float)v0.w + (float)v1.w + (float)v2.w + acc.w);
        __builtin_nontemporal_store(o, reinterpret_cast<f32x4*>(out + rofs));
    }
}

// ---------------------------------------------------------------------------
// Fallback path (ws too small for CSR): unchanged fp32 atomic path.
// ---------------------------------------------------------------------------
__global__ __launch_bounds__(256) void init_kernel(
    const float* __restrict__ user, const float* __restrict__ item,
    float* __restrict__ x, float* __restrict__ out)
{
    const int nu4 = N_USERS * EMB / 4;
    const int nt4 = N_NODES * EMB / 4;
    int i = blockIdx.x * blockDim.x + threadIdx.x;
    if (i >= nt4) return;
    float4 v = (i < nu4) ? reinterpret_cast<const float4*>(user)[i]
                         : reinterpret_cast<const float4*>(item)[i - nu4];
    reinterpret_cast<float4*>(x)[i]   = v;
    reinterpret_cast<float4*>(out)[i] = v;
}

__global__ __launch_bounds__(256) void spmm_atomic_kernel(
    const float* __restrict__ x, const float* __restrict__ val,
    const int* __restrict__ row, const int* __restrict__ col,
    float* __restrict__ y)
{
    int t = blockIdx.x * blockDim.x + threadIdx.x;
    int e = t >> 4;
    if (e >= N_EDGES) return;
    int d = (t & 15) * 4;
    int   r = row[e];
    int   c = col[e];
    float v = val[e];
    float4 xv = *reinterpret_cast<const float4*>(x + c * EMB + d);
    float* yp = y + r * EMB + d;
    unsafeAtomicAdd(yp + 0, v * xv.x);
    unsafeAtomicAdd(yp + 1, v * xv.y);
    unsafeAtomicAdd(yp + 2, v * xv.z);
    unsafeAtomicAdd(yp + 3, v * xv.w);
}

__global__ __launch_bounds__(256) void addscale_kernel(
    const float* __restrict__ xl, float* __restrict__ out, float scale)
{
    const int nt4 = N_NODES * EMB / 4;
    int i = blockIdx.x * blockDim.x + threadIdx.x;
    if (i >= nt4) return;
    float4 a = reinterpret_cast<float4*>(out)[i];
    float4 b = reinterpret_cast<const float4*>(xl)[i];
    a.x = (a.x + b.x) * scale;
    a.y = (a.y + b.y) * scale;
    a.z = (a.z + b.z) * scale;
    a.w = (a.w + b.w) * scale;
    reinterpret_cast<float4*>(out)[i] = a;
}

extern "C" void kernel_launch(void* const* d_in, const int* in_sizes, int n_in,
                              void* d_out, int out_size, void* d_ws, size_t ws_size,
                              hipStream_t stream) {
    const float* emb_user = (const float*)d_in[0];
    const float* emb_item = (const float*)d_in[1];
    const float* edge_val = (const float*)d_in[2];
    const int*   edge_row = (const int*)d_in[3];
    const int*   edge_col = (const int*)d_in[4];
    float* out = (float*)d_out;

    const size_t node_elems = (size_t)N_NODES * EMB;        // 19.2M elems
    char* ws = (char*)d_ws;

    // workspace layout:
    //  region A (76.8 MB): x0 fp16 [0,38.4) | x2 fp16 [38.4,76.8)
    //  region B (76.8 MB): stage 48 MB during build; x1 fp16 [0,38.4) after
    //  packed (bucket-strided): pcol 24 MB + pval 12 MB
    const size_t off_bufA    = 0;
    const size_t off_bufB    = off_bufA + node_elems * sizeof(float);      // 76.8 MB
    const size_t off_pcol    = off_bufB + node_elems * sizeof(float);      // 153.6 MB
    const size_t off_pval    = off_pcol + (size_t)NBUCK * CAP * sizeof(int);
    const size_t off_start   = off_pval + (size_t)NBUCK * CAP * sizeof(f16);
    const size_t off_cnt16   = off_start + (N_NODES + 4) * sizeof(int);
    const size_t off_bcursor = off_cnt16 + (N_NODES + 4) * sizeof(unsigned short);
    const size_t needed      = off_bcursor + (NBUCK + 4) * sizeof(int);    // ~192 MB

    const int nt4       = N_NODES * EMB / 4;
    const int el_blocks = (nt4 + 255) / 256;
    const int e_blocks  = (N_EDGES + 255) / 256;

    static_assert((size_t)NBUCK * CAP * sizeof(SRec) <= (size_t)N_NODES * EMB * sizeof(float),
                  "stage must fit in bufB region");

    if (ws_size >= needed) {
        // ---- CSR path (fp16 tables, strided SoA packed, deferred combine) ----
        f16*  x0buf   = (f16*) (ws + off_bufA);
        f16*  x2buf   = (f16*) (ws + off_bufA) + node_elems;   // +38.4 MB
        f16*  x1buf   = (f16*) (ws + off_bufB);
        int*  pcol    = (int*) (ws + off_pcol);
        f16*  pval    = (f16*) (ws + off_pval);
        int*  start   = (int*) (ws + off_start);
        unsigned short* cnt16 = (unsigned short*)(ws + off_cnt16);
        int*  bcursor = (int*) (ws + off_bcursor);
        SRec* stage   = (SRec*)(ws + off_bufB);   // dead after scatter; x1 reuses

        hipMemsetAsync(bcursor, 0, (NBUCK + 4) * sizeof(int), stream);

        const int bin_blocks = (N_EDGES + BIN_CHUNK - 1) / BIN_CHUNK;      // 306
        fused_init_bin_kernel<<<bin_blocks + INIT_BLOCKS, 256, 0, stream>>>(
            emb_user, emb_item, x0buf,
            (const int4*)edge_row, (const int4*)edge_col, (const float4*)edge_val,
            bcursor, stage, bin_blocks);

        bucket_scan_scatter_kernel<<<NBUCK, 256, 0, stream>>>(
            stage, bcursor, start, cnt16, pcol, pval);

        const int row_blocks = (N_NODES + 15) / 16;
        // L0: x0 -> x1   (x1 overwrites stage: stage is dead after scatter)
        spmm_csr_kernel<<<row_blocks, 256, 0, stream>>>(
            x0buf, pcol, pval, start, cnt16, x1buf, nullptr, nullptr, nullptr, 0);
        // L1: x1 -> x2
        spmm_csr_kernel<<<row_blocks, 256, 0, stream>>>(
            x1buf, pcol, pval, start, cnt16, x2buf, nullptr, nullptr, nullptr, 0);
        // L2: x2 -> epilogue: out = 0.25*(x0+x1+x2+acc), write-only out
        spmm_csr_kernel<<<row_blocks, 256, 0, stream>>>(
            x2buf, pcol, pval, start, cnt16, nullptr, x0buf, x1buf, out, 1);
    } else {
        // ---- fallback: fp32 atomic path (needs only 153.6 MB) ----
        float* fbufA = (float*)(ws + off_bufA);
        float* fbufB = (float*)(ws + off_bufB);
        init_kernel<<<el_blocks, 256, 0, stream>>>(emb_user, emb_item, fbufA, out);
        const int ew_blocks = (N_EDGES * 16 + 255) / 256;
        float* cur = fbufA;
        float* nxt = fbufB;
        for (int layer = 0; layer < 3; ++layer) {
            hipMemsetAsync(nxt, 0, node_elems * sizeof(float), stream);
            spmm_atomic_kernel<<<ew_blocks, 256, 0, stream>>>(
                cur, edge_val, edge_row, edge_col, nxt);
            addscale_kernel<<<el_blocks, 256, 0, stream>>>(
                nxt, out, (layer == 2) ? 0.25f : 1.0f);
            float* tmp = cur; cur = nxt; nxt = tmp;
        }
    }
}

// Round 11
// 549.555 us; speedup vs baseline: 1.0363x; 1.0363x over previous
//
#include <hip/hip_runtime.h>

#define N_USERS 200000
#define N_ITEMS 100000
#define N_NODES 300000
#define EMB     64
#define N_EDGES 5000000

typedef float f32x4 __attribute__((ext_vector_type(4)));
typedef _Float16 f16;
typedef f16 f16x4 __attribute__((ext_vector_type(4)));     // 8 B gather granule

// 8 B staged record: rc = (rowLow10 << 19) | col  (col < 2^19)
struct alignas(8) SRec { unsigned int rc; float val; };

#define BSHIFT 10
#define BROWS  (1 << BSHIFT)                               // 1024
#define NBUCK  ((N_NODES + BROWS - 1) >> BSHIFT)           // 293
#define CAP    20000                                       // mean 17065 (+22 sigma)
#define BIN_CHUNK 16384                                    // edges per bin block
#define BIN_THREADS 1024                                   // 16 waves/CU (was 4!)
#define COLMASK 0x7FFFFu
#define INIT_BLOCKS 512                                    // grid-strided init part

// ---------------------------------------------------------------------------
// Fused init + bin.
// R10 PMC post-mortem: (a) BSHIFT 8 claims were 112 B sub-line -> WRITE 170 MB
// (3.3x amp); reverted to BSHIFT 10 (448 B runs). (b) 306 blocks x 256 thr
// = 4 waves/CU -> nothing to hide latency (Occ 35%, VALU 3%); now 1024 thr
// = 16 waves/CU, 16 edges/thread so each thread's loads batch fully.
// ---------------------------------------------------------------------------
__global__ __launch_bounds__(1024) void fused_init_bin_kernel(
    const float* __restrict__ user, const float* __restrict__ item,
    f16* __restrict__ x0,
    const int4* __restrict__ row4, const int4* __restrict__ col4,
    const float4* __restrict__ val4,
    int* __restrict__ bcursor, SRec* __restrict__ stage, int bin_blocks)
{
    int t = threadIdx.x;
    if ((int)blockIdx.x < bin_blocks) {
        __shared__ int hist[NBUCK];
        __shared__ int base_[NBUCK];
        const int Q = N_EDGES / 4;                    // int4 count (N_EDGES%4==0)
        long q0 = (long)blockIdx.x * (BIN_CHUNK / 4); // 4096 int4 / block

        for (int k = t; k < NBUCK; k += BIN_THREADS) hist[k] = 0;
        __syncthreads();

        // ---- pass A: batch 4 row loads, count 16K edges ----
        int4 ra[4];
        const bool full = (q0 + (BIN_CHUNK / 4) <= Q);
        if (full) {
            #pragma unroll
            for (int k = 0; k < 4; ++k)
                ra[k] = row4[q0 + k * BIN_THREADS + t];
            #pragma unroll
            for (int k = 0; k < 4; ++k) {
                atomicAdd(&hist[ra[k].x >> BSHIFT], 1);
                atomicAdd(&hist[ra[k].y >> BSHIFT], 1);
                atomicAdd(&hist[ra[k].z >> BSHIFT], 1);
                atomicAdd(&hist[ra[k].w >> BSHIFT], 1);
            }
        } else {
            #pragma unroll
            for (int k = 0; k < 4; ++k) {
                long q = q0 + k * BIN_THREADS + t;
                if (q < Q) {
                    ra[k] = row4[q];
                    atomicAdd(&hist[ra[k].x >> BSHIFT], 1);
                    atomicAdd(&hist[ra[k].y >> BSHIFT], 1);
                    atomicAdd(&hist[ra[k].z >> BSHIFT], 1);
                    atomicAdd(&hist[ra[k].w >> BSHIFT], 1);
                }
            }
        }
        __syncthreads();
        // one claim per bucket for the whole 16K chunk -> 448 B dense runs
        for (int k = t; k < NBUCK; k += BIN_THREADS) {
            int h = hist[k];
            base_[k] = h ? atomicAdd(&bcursor[k], h) : 0;
            hist[k] = 0;                               // reuse as local cursor
        }
        __syncthreads();
        // ---- pass B: batch col/val loads (8 in flight), scatter ----
        int4 c4[4]; float4 v4[4];
        if (full) {
            #pragma unroll
            for (int k = 0; k < 4; ++k) {
                c4[k] = col4[q0 + k * BIN_THREADS + t];
                v4[k] = val4[q0 + k * BIN_THREADS + t];
            }
        } else {
            #pragma unroll
            for (int k = 0; k < 4; ++k) {
                long q = q0 + k * BIN_THREADS + t;
                if (q < Q) { c4[k] = col4[q]; v4[k] = val4[q]; }
            }
        }
        #pragma unroll
        for (int k = 0; k < 4; ++k) {
            long q = q0 + k * BIN_THREADS + t;
            if (full || q < Q) {
                int   rr[4] = {ra[k].x, ra[k].y, ra[k].z, ra[k].w};
                int   cc[4] = {c4[k].x, c4[k].y, c4[k].z, c4[k].w};
                float vv[4] = {v4[k].x, v4[k].y, v4[k].z, v4[k].w};
                #pragma unroll
                for (int m = 0; m < 4; ++m) {
                    int b   = rr[m] >> BSHIFT;
                    int pos = base_[b] + atomicAdd(&hist[b], 1);
                    SRec s;
                    s.rc  = ((unsigned)(rr[m] & (BROWS - 1)) << 19)
                          | (unsigned)cc[m];
                    s.val = vv[m];
                    stage[(size_t)b * CAP + pos] = s;
                }
            }
        }
    } else {
        const int nu4 = N_USERS * EMB / 4;
        const int nt4 = N_NODES * EMB / 4;
        int i0 = ((int)blockIdx.x - bin_blocks) * BIN_THREADS + t;
        const int stride = INIT_BLOCKS * BIN_THREADS;
        for (int i = i0; i < nt4; i += stride) {
            float4 vv = (i < nu4) ? reinterpret_cast<const float4*>(user)[i]
                                  : reinterpret_cast<const float4*>(item)[i - nu4];
            f16x4 hx = {(f16)vv.x, (f16)vv.y, (f16)vv.z, (f16)vv.w};
            reinterpret_cast<f16x4*>(x0)[i] = hx;
        }
    }
}

// ---------------------------------------------------------------------------
// Per-bucket (1024 rows): count -> 1024-wide scan -> LDS row-sort -> dense
// stream-out to BUCKET-STRIDED packed (pos = b*CAP + local; no inter-bucket
// prefix, cnt16[] carries row degrees). LDS ~128 KiB: lcol 80K + lval 40K.
// R9-proven structure + R10's strided/cnt16 simplification.
// ---------------------------------------------------------------------------
__global__ __launch_bounds__(1024) void bucket_scan_scatter_kernel(
    const SRec* __restrict__ stage, const int* __restrict__ bsize,
    int* __restrict__ start, unsigned short* __restrict__ cnt16,
    int* __restrict__ pcol, f16* __restrict__ pval)
{
    __shared__ int cur[BROWS];          // counts -> cursors
    __shared__ int sc[1024];
    __shared__ int lcol[CAP];           // 80 KB
    __shared__ f16 lval[CAP];           // 40 KB

    int b    = blockIdx.x;
    int t    = threadIdx.x;
    int row0 = b << BSHIFT;
    int rows = N_NODES - row0; if (rows > BROWS) rows = BROWS;

    const int  size = bsize[b];
    const int  base = b * CAP;
    const SRec* seg = stage + (size_t)b * CAP;

    cur[t] = 0;
    __syncthreads();

    // pass A: per-row counts
    for (int e = t; e < size; e += 1024)
        atomicAdd(&cur[seg[e].rc >> 19], 1);
    __syncthreads();

    // exclusive scan over 1024 counts
    int a = cur[t];
    sc[t] = a;
    __syncthreads();
    for (int ofs = 1; ofs < 1024; ofs <<= 1) {
        int v = (t >= ofs) ? sc[t - ofs] : 0;
        __syncthreads();
        sc[t] += v;
        __syncthreads();
    }
    int excl = sc[t] - a;
    cur[t] = excl;                      // local cursor
    if (t < rows) {
        start[row0 + t] = base + excl;  // strided global offset
        cnt16[row0 + t] = (unsigned short)a;
    }
    __syncthreads();

    // pass B: row-sort into LDS (seg L2-warm from pass A)
    for (int e = t; e < size; e += 1024) {
        SRec srec = seg[e];
        int idx = atomicAdd(&cur[srec.rc >> 19], 1);
        lcol[idx] = (int)(srec.rc & COLMASK);
        lval[idx] = (f16)srec.val;
    }
    __syncthreads();

    // stream out: dense, coalesced, payload-only
    for (int i = t; i < size; i += 1024) pcol[base + i] = lcol[i];
    for (int i = t; i < size; i += 1024) pval[base + i] = lval[i];
}

// ---------------------------------------------------------------------------
// CSR SpMM over fp16 tables (strided CSR: beg = start[g], end = beg+cnt16[g]).
// mode 0: write y only. mode 1 (layer 2): out = 0.25*(x0+x1+x2+acc).
// Established floor: compulsory miss-path bytes (8 XCD x table + packed) at
// ~3.9 TB/s pattern rate; L2 already captures all gather reuse.
// ---------------------------------------------------------------------------
__global__ __launch_bounds__(256, 4) void spmm_csr_kernel(
    const f16* __restrict__ x, const int* __restrict__ pcol,
    const f16* __restrict__ pval, const int* __restrict__ start,
    const unsigned short* __restrict__ cnt16,
    f16* __restrict__ y,
    const f16* __restrict__ xa, const f16* __restrict__ xb,
    float* __restrict__ out, int mode)
{
    int g = blockIdx.x * (256 / 16) + (threadIdx.x >> 4);
    if (g >= N_NODES) return;
    const int lane16 = threadIdx.x & 15;
    const int d      = lane16 * 4;
    const int gbase  = threadIdx.x & 48;

    int beg = start[g];
    int end = beg + cnt16[g];
    float4 acc = {0.f, 0.f, 0.f, 0.f};

    for (int jb = beg; jb < end; jb += 16) {
        int   mycol = 0; float myval = 0.f;
        if (jb + lane16 < end) {
            mycol = pcol[jb + lane16];
            myval = (float)pval[jb + lane16];
        }

        int   cols[16];
        float vals[16];
        #pragma unroll
        for (int k = 0; k < 16; ++k) {
            cols[k] = __shfl(mycol, gbase + k, 64);
            vals[k] = __shfl(myval, gbase + k, 64);
        }

        f16x4 xv[16];
        #pragma unroll
        for (int k = 0; k < 16; ++k) {
            xv[k] = *reinterpret_cast<const f16x4*>(
                x + (size_t)cols[k] * EMB + d);
        }

        #pragma unroll
        for (int k = 0; k < 16; ++k) {
            acc.x += vals[k] * (float)xv[k].x;
            acc.y += vals[k] * (float)xv[k].y;
            acc.z += vals[k] * (float)xv[k].z;
            acc.w += vals[k] * (float)xv[k].w;
        }
    }

    const size_t rofs = (size_t)g * EMB + d;
    if (mode == 0) {
        f16x4 hy = {(f16)acc.x, (f16)acc.y, (f16)acc.z, (f16)acc.w};
        *reinterpret_cast<f16x4*>(y + rofs) = hy;
    } else {
        f16x4 v0 = *reinterpret_cast<const f16x4*>(xa + rofs);
        f16x4 v1 = *reinterpret_cast<const f16x4*>(xb + rofs);
        f16x4 v2 = *reinterpret_cast<const f16x4*>(x  + rofs);
        f32x4 o;
        o.x = 0.25f * ((float)v0.x + (float)v1.x + (float)v2.x + acc.x);
        o.y = 0.25f * ((float)v0.y + (float)v1.y + (float)v2.y + acc.y);
        o.z = 0.25f * ((float)v0.z + (float)v1.z + (float)v2.z + acc.z);
        o.w = 0.25f * ((float)v0.w + (float)v1.w + (float)v2.w + acc.w);
        __builtin_nontemporal_store(o, reinterpret_cast<f32x4*>(out + rofs));
    }
}

// ---------------------------------------------------------------------------
// Fallback path (ws too small for CSR): unchanged fp32 atomic path.
// ---------------------------------------------------------------------------
__global__ __launch_bounds__(256) void init_kernel(
    const float* __restrict__ user, const float* __restrict__ item,
    float* __restrict__ x, float* __restrict__ out)
{
    const int nu4 = N_USERS * EMB / 4;
    const int nt4 = N_NODES * EMB / 4;
    int i = blockIdx.x * blockDim.x + threadIdx.x;
    if (i >= nt4) return;
    float4 v = (i < nu4) ? reinterpret_cast<const float4*>(user)[i]
                         : reinterpret_cast<const float4*>(item)[i - nu4];
    reinterpret_cast<float4*>(x)[i]   = v;
    reinterpret_cast<float4*>(out)[i] = v;
}

__global__ __launch_bounds__(256) void spmm_atomic_kernel(
    const float* __restrict__ x, const float* __restrict__ val,
    const int* __restrict__ row, const int* __restrict__ col,
    float* __restrict__ y)
{
    int t = blockIdx.x * blockDim.x + threadIdx.x;
    int e = t >> 4;
    if (e >= N_EDGES) return;
    int d = (t & 15) * 4;
    int   r = row[e];
    int   c = col[e];
    float v = val[e];
    float4 xv = *reinterpret_cast<const float4*>(x + c * EMB + d);
    float* yp = y + r * EMB + d;
    unsafeAtomicAdd(yp + 0, v * xv.x);
    unsafeAtomicAdd(yp + 1, v * xv.y);
    unsafeAtomicAdd(yp + 2, v * xv.z);
    unsafeAtomicAdd(yp + 3, v * xv.w);
}

__global__ __launch_bounds__(256) void addscale_kernel(
    const float* __restrict__ xl, float* __restrict__ out, float scale)
{
    const int nt4 = N_NODES * EMB / 4;
    int i = blockIdx.x * blockDim.x + threadIdx.x;
    if (i >= nt4) return;
    float4 a = reinterpret_cast<float4*>(out)[i];
    float4 b = reinterpret_cast<const float4*>(xl)[i];
    a.x = (a.x + b.x) * scale;
    a.y = (a.y + b.y) * scale;
    a.z = (a.z + b.z) * scale;
    a.w = (a.w + b.w) * scale;
    reinterpret_cast<float4*>(out)[i] = a;
}

extern "C" void kernel_launch(void* const* d_in, const int* in_sizes, int n_in,
                              void* d_out, int out_size, void* d_ws, size_t ws_size,
                              hipStream_t stream) {
    const float* emb_user = (const float*)d_in[0];
    const float* emb_item = (const float*)d_in[1];
    const float* edge_val = (const float*)d_in[2];
    const int*   edge_row = (const int*)d_in[3];
    const int*   edge_col = (const int*)d_in[4];
    float* out = (float*)d_out;

    const size_t node_elems = (size_t)N_NODES * EMB;        // 19.2M elems
    char* ws = (char*)d_ws;

    // workspace layout:
    //  region A (76.8 MB): x0 fp16 [0,38.4) | x2 fp16 [38.4,76.8)
    //  region B (76.8 MB): stage 47 MB during build; x1 fp16 [0,38.4) after
    //  packed (bucket-strided): pcol 23.4 MB + pval 11.7 MB
    const size_t off_bufA    = 0;
    const size_t off_bufB    = off_bufA + node_elems * sizeof(float);      // 76.8 MB
    const size_t off_pcol    = off_bufB + node_elems * sizeof(float);      // 153.6 MB
    const size_t off_pval    = off_pcol + (size_t)NBUCK * CAP * sizeof(int);
    const size_t off_start   = off_pval + (size_t)NBUCK * CAP * sizeof(f16);
    const size_t off_cnt16   = off_start + (N_NODES + 4) * sizeof(int);
    const size_t off_bcursor = off_cnt16 + (N_NODES + 4) * sizeof(unsigned short);
    const size_t needed      = off_bcursor + (NBUCK + 4) * sizeof(int);    // ~191 MB

    const int nt4       = N_NODES * EMB / 4;
    const int el_blocks = (nt4 + 255) / 256;
    const int e_blocks  = (N_EDGES + 255) / 256;

    static_assert((size_t)NBUCK * CAP * sizeof(SRec) <= (size_t)N_NODES * EMB * sizeof(float),
                  "stage must fit in bufB region");

    if (ws_size >= needed) {
        // ---- CSR path (fp16 tables, strided SoA packed, deferred combine) ----
        f16*  x0buf   = (f16*) (ws + off_bufA);
        f16*  x2buf   = (f16*) (ws + off_bufA) + node_elems;   // +38.4 MB
        f16*  x1buf   = (f16*) (ws + off_bufB);
        int*  pcol    = (int*) (ws + off_pcol);
        f16*  pval    = (f16*) (ws + off_pval);
        int*  start   = (int*) (ws + off_start);
        unsigned short* cnt16 = (unsigned short*)(ws + off_cnt16);
        int*  bcursor = (int*) (ws + off_bcursor);
        SRec* stage   = (SRec*)(ws + off_bufB);   // dead after scatter; x1 reuses

        hipMemsetAsync(bcursor, 0, (NBUCK + 4) * sizeof(int), stream);

        const int bin_blocks = (N_EDGES + BIN_CHUNK - 1) / BIN_CHUNK;      // 306
        fused_init_bin_kernel<<<bin_blocks + INIT_BLOCKS, BIN_THREADS, 0, stream>>>(
            emb_user, emb_item, x0buf,
            (const int4*)edge_row, (const int4*)edge_col, (const float4*)edge_val,
            bcursor, stage, bin_blocks);

        bucket_scan_scatter_kernel<<<NBUCK, 1024, 0, stream>>>(
            stage, bcursor, start, cnt16, pcol, pval);

        const int row_blocks = (N_NODES + 15) / 16;
        // L0: x0 -> x1   (x1 overwrites stage: stage is dead after scatter)
        spmm_csr_kernel<<<row_blocks, 256, 0, stream>>>(
            x0buf, pcol, pval, start, cnt16, x1buf, nullptr, nullptr, nullptr, 0);
        // L1: x1 -> x2
        spmm_csr_kernel<<<row_blocks, 256, 0, stream>>>(
            x1buf, pcol, pval, start, cnt16, x2buf, nullptr, nullptr, nullptr, 0);
        // L2: x2 -> epilogue: out = 0.25*(x0+x1+x2+acc), write-only out
        spmm_csr_kernel<<<row_blocks, 256, 0, stream>>>(
            x2buf, pcol, pval, start, cnt16, nullptr, x0buf, x1buf, out, 1);
    } else {
        // ---- fallback: fp32 atomic path (needs only 153.6 MB) ----
        float* fbufA = (float*)(ws + off_bufA);
        float* fbufB = (float*)(ws + off_bufB);
        init_kernel<<<el_blocks, 256, 0, stream>>>(emb_user, emb_item, fbufA, out);
        const int ew_blocks = (N_EDGES * 16 + 255) / 256;
        float* cur = fbufA;
        float* nxt = fbufB;
        for (int layer = 0; layer < 3; ++layer) {
            hipMemsetAsync(nxt, 0, node_elems * sizeof(float), stream);
            spmm_atomic_kernel<<<ew_blocks, 256, 0, stream>>>(
                cur, edge_val, edge_row, edge_col, nxt);
            addscale_kernel<<<el_blocks, 256, 0, stream>>>(
                nxt, out, (layer == 2) ? 0.25f : 1.0f);
            float* tmp = cur; cur = nxt; nxt = tmp;
        }
    }
}

// Round 12
// 530.881 us; speedup vs baseline: 1.0727x; 1.0352x over previous
//
#include <hip/hip_runtime.h>

#define N_USERS 200000
#define N_ITEMS 100000
#define N_NODES 300000
#define EMB     64
#define N_EDGES 5000000

typedef float f32x4 __attribute__((ext_vector_type(4)));
typedef _Float16 f16;
typedef f16 f16x4 __attribute__((ext_vector_type(4)));     // 8 B gather granule

// 8 B staged record: rc = (rowLow10 << 19) | col  (col < 2^19)
struct alignas(8) SRec { unsigned int rc; float val; };

#define BSHIFT 10
#define BROWS  (1 << BSHIFT)                               // 1024
#define NBUCK  ((N_NODES + BROWS - 1) >> BSHIFT)           // 293
#define CAP    20000                                       // mean 17065 (+22 sigma)
#define BIN_CHUNK 16384                                    // edges per bin block
#define BIN_THREADS 1024
#define COLMASK 0x7FFFFu
#define INIT_BLOCKS 512                                    // grid-strided init part

// ---------------------------------------------------------------------------
// Fused init + bin.
// R10 PMC model: bin = (67+170) MB at 2.0 TB/s -> the scattered 8 B SRec
// stores ARE the cost (8 B-random pattern rate ~2 TB/s). This round: sort the
// 16K edges into a 128 KB LDS buffer by bucket, claim each bucket run once,
// then BURST out dense (consecutive threads -> consecutive addresses, full
// 128 B lines) — same fix that took scatter's write amp 10x -> 1x in R9.
// Bucket id on the way out: 9-step binary search over lstart[] in LDS.
// ---------------------------------------------------------------------------
__global__ __launch_bounds__(1024) void fused_init_bin_kernel(
    const float* __restrict__ user, const float* __restrict__ item,
    f16* __restrict__ x0,
    const int4* __restrict__ row4, const int4* __restrict__ col4,
    const float4* __restrict__ val4,
    int* __restrict__ bcursor, SRec* __restrict__ stage, int bin_blocks)
{
    int t = threadIdx.x;
    if ((int)blockIdx.x < bin_blocks) {
        __shared__ int  hist[NBUCK];        // counts -> sort cursors
        __shared__ int  lstart[NBUCK + 1];  // local exclusive offsets
        __shared__ int  gbase[NBUCK];       // claimed global run bases
        __shared__ int  sc[512];            // scan workspace
        __shared__ SRec sbuf[BIN_CHUNK];    // 128 KB bucket-sorted staging

        const int Q = N_EDGES / 4;                    // int4 count (N_EDGES%4==0)
        long q0 = (long)blockIdx.x * (BIN_CHUNK / 4); // 4096 int4 / block
        int  csize = N_EDGES - (int)(q0 * 4);
        if (csize > BIN_CHUNK) csize = BIN_CHUNK;

        for (int k = t; k < NBUCK; k += BIN_THREADS) hist[k] = 0;
        __syncthreads();

        // ---- pass A: batch row loads, count ----
        int4 ra[4];
        const bool full = (q0 + (BIN_CHUNK / 4) <= Q);
        if (full) {
            #pragma unroll
            for (int k = 0; k < 4; ++k)
                ra[k] = row4[q0 + k * BIN_THREADS + t];
            #pragma unroll
            for (int k = 0; k < 4; ++k) {
                atomicAdd(&hist[ra[k].x >> BSHIFT], 1);
                atomicAdd(&hist[ra[k].y >> BSHIFT], 1);
                atomicAdd(&hist[ra[k].z >> BSHIFT], 1);
                atomicAdd(&hist[ra[k].w >> BSHIFT], 1);
            }
        } else {
            #pragma unroll
            for (int k = 0; k < 4; ++k) {
                long q = q0 + k * BIN_THREADS + t;
                if (q < Q) {
                    ra[k] = row4[q];
                    atomicAdd(&hist[ra[k].x >> BSHIFT], 1);
                    atomicAdd(&hist[ra[k].y >> BSHIFT], 1);
                    atomicAdd(&hist[ra[k].z >> BSHIFT], 1);
                    atomicAdd(&hist[ra[k].w >> BSHIFT], 1);
                }
            }
        }
        __syncthreads();

        // ---- exclusive scan over NBUCK counts (512-thread Hillis-Steele) ----
        int v = (t < NBUCK) ? hist[t] : 0;
        if (t < 512) sc[t] = v;
        __syncthreads();
        for (int ofs = 1; ofs < 512; ofs <<= 1) {
            int u = 0;
            if (t < 512 && t >= ofs) u = sc[t - ofs];
            __syncthreads();
            if (t < 512) sc[t] += u;
            __syncthreads();
        }
        if (t < NBUCK) lstart[t] = sc[t] - v;
        if (t == NBUCK - 1) lstart[NBUCK] = sc[t];
        __syncthreads();
        // claim global runs; hist becomes the local sort cursor
        if (t < NBUCK) {
            gbase[t] = v ? atomicAdd(&bcursor[t], v) : 0;
            hist[t]  = lstart[t];
        }
        __syncthreads();

        // ---- pass B: batch col/val loads, sort into LDS by bucket ----
        int4 c4[4]; float4 v4[4];
        if (full) {
            #pragma unroll
            for (int k = 0; k < 4; ++k) {
                c4[k] = col4[q0 + k * BIN_THREADS + t];
                v4[k] = val4[q0 + k * BIN_THREADS + t];
            }
        } else {
            #pragma unroll
            for (int k = 0; k < 4; ++k) {
                long q = q0 + k * BIN_THREADS + t;
                if (q < Q) { c4[k] = col4[q]; v4[k] = val4[q]; }
            }
        }
        #pragma unroll
        for (int k = 0; k < 4; ++k) {
            long q = q0 + k * BIN_THREADS + t;
            if (full || q < Q) {
                int   rr[4] = {ra[k].x, ra[k].y, ra[k].z, ra[k].w};
                int   cc[4] = {c4[k].x, c4[k].y, c4[k].z, c4[k].w};
                float vv[4] = {v4[k].x, v4[k].y, v4[k].z, v4[k].w};
                #pragma unroll
                for (int m = 0; m < 4; ++m) {
                    int b   = rr[m] >> BSHIFT;
                    int idx = atomicAdd(&hist[b], 1);
                    SRec s;
                    s.rc  = ((unsigned)(rr[m] & (BROWS - 1)) << 19)
                          | (unsigned)cc[m];
                    s.val = vv[m];
                    sbuf[idx] = s;
                }
            }
        }
        __syncthreads();

        // ---- burst out: dense, line-coalesced stage writes ----
        for (int i = t; i < csize; i += BIN_THREADS) {
            int lo = 0, hi = NBUCK - 1;        // largest b with lstart[b] <= i
            while (lo < hi) {
                int mid = (lo + hi + 1) >> 1;
                if (lstart[mid] <= i) lo = mid; else hi = mid - 1;
            }
            stage[(size_t)lo * CAP + gbase[lo] + (i - lstart[lo])] = sbuf[i];
        }
    } else {
        const int nu4 = N_USERS * EMB / 4;
        const int nt4 = N_NODES * EMB / 4;
        int i0 = ((int)blockIdx.x - bin_blocks) * BIN_THREADS + t;
        const int stride = INIT_BLOCKS * BIN_THREADS;
        for (int i = i0; i < nt4; i += stride) {
            float4 vv = (i < nu4) ? reinterpret_cast<const float4*>(user)[i]
                                  : reinterpret_cast<const float4*>(item)[i - nu4];
            f16x4 hx = {(f16)vv.x, (f16)vv.y, (f16)vv.z, (f16)vv.w};
            reinterpret_cast<f16x4*>(x0)[i] = hx;
        }
    }
}

// ---------------------------------------------------------------------------
// Per-bucket (1024 rows): count -> 1024-wide scan -> LDS row-sort -> dense
// stream-out to BUCKET-STRIDED packed (pos = b*CAP + local; no inter-bucket
// prefix, cnt16[] carries row degrees). LDS ~128 KiB.
// ---------------------------------------------------------------------------
__global__ __launch_bounds__(1024) void bucket_scan_scatter_kernel(
    const SRec* __restrict__ stage, const int* __restrict__ bsize,
    int* __restrict__ start, unsigned short* __restrict__ cnt16,
    int* __restrict__ pcol, f16* __restrict__ pval)
{
    __shared__ int cur[BROWS];          // counts -> cursors
    __shared__ int sc[1024];
    __shared__ int lcol[CAP];           // 80 KB
    __shared__ f16 lval[CAP];           // 40 KB

    int b    = blockIdx.x;
    int t    = threadIdx.x;
    int row0 = b << BSHIFT;
    int rows = N_NODES - row0; if (rows > BROWS) rows = BROWS;

    const int  size = bsize[b];
    const int  base = b * CAP;
    const SRec* seg = stage + (size_t)b * CAP;

    cur[t] = 0;
    __syncthreads();

    // pass A: per-row counts
    for (int e = t; e < size; e += 1024)
        atomicAdd(&cur[seg[e].rc >> 19], 1);
    __syncthreads();

    // exclusive scan over 1024 counts
    int a = cur[t];
    sc[t] = a;
    __syncthreads();
    for (int ofs = 1; ofs < 1024; ofs <<= 1) {
        int v = (t >= ofs) ? sc[t - ofs] : 0;
        __syncthreads();
        sc[t] += v;
        __syncthreads();
    }
    int excl = sc[t] - a;
    cur[t] = excl;                      // local cursor
    if (t < rows) {
        start[row0 + t] = base + excl;  // strided global offset
        cnt16[row0 + t] = (unsigned short)a;
    }
    __syncthreads();

    // pass B: row-sort into LDS (seg L2-warm from pass A)
    for (int e = t; e < size; e += 1024) {
        SRec srec = seg[e];
        int idx = atomicAdd(&cur[srec.rc >> 19], 1);
        lcol[idx] = (int)(srec.rc & COLMASK);
        lval[idx] = (f16)srec.val;
    }
    __syncthreads();

    // stream out: dense, coalesced, payload-only
    for (int i = t; i < size; i += 1024) pcol[base + i] = lcol[i];
    for (int i = t; i < size; i += 1024) pval[base + i] = lval[i];
}

// ---------------------------------------------------------------------------
// CSR SpMM over fp16 tables (strided CSR: beg = start[g], end = beg+cnt16[g]).
// mode 0: write y only. mode 1 (layer 2): out = 0.25*(x0+x1+x2+acc).
// Established floor: compulsory miss-path bytes (8 XCD x table + packed) at
// ~3.9 TB/s pattern rate; L2 already captures all gather reuse.
// ---------------------------------------------------------------------------
__global__ __launch_bounds__(256, 4) void spmm_csr_kernel(
    const f16* __restrict__ x, const int* __restrict__ pcol,
    const f16* __restrict__ pval, const int* __restrict__ start,
    const unsigned short* __restrict__ cnt16,
    f16* __restrict__ y,
    const f16* __restrict__ xa, const f16* __restrict__ xb,
    float* __restrict__ out, int mode)
{
    int g = blockIdx.x * (256 / 16) + (threadIdx.x >> 4);
    if (g >= N_NODES) return;
    const int lane16 = threadIdx.x & 15;
    const int d      = lane16 * 4;
    const int gbase  = threadIdx.x & 48;

    int beg = start[g];
    int end = beg + cnt16[g];
    float4 acc = {0.f, 0.f, 0.f, 0.f};

    for (int jb = beg; jb < end; jb += 16) {
        int   mycol = 0; float myval = 0.f;
        if (jb + lane16 < end) {
            mycol = pcol[jb + lane16];
            myval = (float)pval[jb + lane16];
        }

        int   cols[16];
        float vals[16];
        #pragma unroll
        for (int k = 0; k < 16; ++k) {
            cols[k] = __shfl(mycol, gbase + k, 64);
            vals[k] = __shfl(myval, gbase + k, 64);
        }

        f16x4 xv[16];
        #pragma unroll
        for (int k = 0; k < 16; ++k) {
            xv[k] = *reinterpret_cast<const f16x4*>(
                x + (size_t)cols[k] * EMB + d);
        }

        #pragma unroll
        for (int k = 0; k < 16; ++k) {
            acc.x += vals[k] * (float)xv[k].x;
            acc.y += vals[k] * (float)xv[k].y;
            acc.z += vals[k] * (float)xv[k].z;
            acc.w += vals[k] * (float)xv[k].w;
        }
    }

    const size_t rofs = (size_t)g * EMB + d;
    if (mode == 0) {
        f16x4 hy = {(f16)acc.x, (f16)acc.y, (f16)acc.z, (f16)acc.w};
        *reinterpret_cast<f16x4*>(y + rofs) = hy;
    } else {
        f16x4 v0 = *reinterpret_cast<const f16x4*>(xa + rofs);
        f16x4 v1 = *reinterpret_cast<const f16x4*>(xb + rofs);
        f16x4 v2 = *reinterpret_cast<const f16x4*>(x  + rofs);
        f32x4 o;
        o.x = 0.25f * ((float)v0.x + (float)v1.x + (float)v2.x + acc.x);
        o.y = 0.25f * ((float)v0.y + (float)v1.y + (float)v2.y + acc.y);
        o.z = 0.25f * ((float)v0.z + (float)v1.z + (float)v2.z + acc.z);
        o.w = 0.25f * ((float)v0.w + (float)v1.w + (float)v2.w + acc.w);
        __builtin_nontemporal_store(o, reinterpret_cast<f32x4*>(out + rofs));
    }
}

// ---------------------------------------------------------------------------
// Fallback path (ws too small for CSR): unchanged fp32 atomic path.
// ---------------------------------------------------------------------------
__global__ __launch_bounds__(256) void init_kernel(
    const float* __restrict__ user, const float* __restrict__ item,
    float* __restrict__ x, float* __restrict__ out)
{
    const int nu4 = N_USERS * EMB / 4;
    const int nt4 = N_NODES * EMB / 4;
    int i = blockIdx.x * blockDim.x + threadIdx.x;
    if (i >= nt4) return;
    float4 v = (i < nu4) ? reinterpret_cast<const float4*>(user)[i]
                         : reinterpret_cast<const float4*>(item)[i - nu4];
    reinterpret_cast<float4*>(x)[i]   = v;
    reinterpret_cast<float4*>(out)[i] = v;
}

__global__ __launch_bounds__(256) void spmm_atomic_kernel(
    const float* __restrict__ x, const float* __restrict__ val,
    const int* __restrict__ row, const int* __restrict__ col,
    float* __restrict__ y)
{
    int t = blockIdx.x * blockDim.x + threadIdx.x;
    int e = t >> 4;
    if (e >= N_EDGES) return;
    int d = (t & 15) * 4;
    int   r = row[e];
    int   c = col[e];
    float v = val[e];
    float4 xv = *reinterpret_cast<const float4*>(x + c * EMB + d);
    float* yp = y + r * EMB + d;
    unsafeAtomicAdd(yp + 0, v * xv.x);
    unsafeAtomicAdd(yp + 1, v * xv.y);
    unsafeAtomicAdd(yp + 2, v * xv.z);
    unsafeAtomicAdd(yp + 3, v * xv.w);
}

__global__ __launch_bounds__(256) void addscale_kernel(
    const float* __restrict__ xl, float* __restrict__ out, float scale)
{
    const int nt4 = N_NODES * EMB / 4;
    int i = blockIdx.x * blockDim.x + threadIdx.x;
    if (i >= nt4) return;
    float4 a = reinterpret_cast<float4*>(out)[i];
    float4 b = reinterpret_cast<const float4*>(xl)[i];
    a.x = (a.x + b.x) * scale;
    a.y = (a.y + b.y) * scale;
    a.z = (a.z + b.z) * scale;
    a.w = (a.w + b.w) * scale;
    reinterpret_cast<float4*>(out)[i] = a;
}

extern "C" void kernel_launch(void* const* d_in, const int* in_sizes, int n_in,
                              void* d_out, int out_size, void* d_ws, size_t ws_size,
                              hipStream_t stream) {
    const float* emb_user = (const float*)d_in[0];
    const float* emb_item = (const float*)d_in[1];
    const float* edge_val = (const float*)d_in[2];
    const int*   edge_row = (const int*)d_in[3];
    const int*   edge_col = (const int*)d_in[4];
    float* out = (float*)d_out;

    const size_t node_elems = (size_t)N_NODES * EMB;        // 19.2M elems
    char* ws = (char*)d_ws;

    // workspace layout:
    //  region A (76.8 MB): x0 fp16 [0,38.4) | x2 fp16 [38.4,76.8)
    //  region B (76.8 MB): stage 47 MB during build; x1 fp16 [0,38.4) after
    //  packed (bucket-strided): pcol 23.4 MB + pval 11.7 MB
    const size_t off_bufA    = 0;
    const size_t off_bufB    = off_bufA + node_elems * sizeof(float);      // 76.8 MB
    const size_t off_pcol    = off_bufB + node_elems * sizeof(float);      // 153.6 MB
    const size_t off_pval    = off_pcol + (size_t)NBUCK * CAP * sizeof(int);
    const size_t off_start   = off_pval + (size_t)NBUCK * CAP * sizeof(f16);
    const size_t off_cnt16   = off_start + (N_NODES + 4) * sizeof(int);
    const size_t off_bcursor = off_cnt16 + (N_NODES + 4) * sizeof(unsigned short);
    const size_t needed      = off_bcursor + (NBUCK + 4) * sizeof(int);    // ~191 MB

    const int nt4       = N_NODES * EMB / 4;
    const int el_blocks = (nt4 + 255) / 256;
    const int e_blocks  = (N_EDGES + 255) / 256;

    static_assert((size_t)NBUCK * CAP * sizeof(SRec) <= (size_t)N_NODES * EMB * sizeof(float),
                  "stage must fit in bufB region");

    if (ws_size >= needed) {
        // ---- CSR path (fp16 tables, strided SoA packed, deferred combine) ----
        f16*  x0buf   = (f16*) (ws + off_bufA);
        f16*  x2buf   = (f16*) (ws + off_bufA) + node_elems;   // +38.4 MB
        f16*  x1buf   = (f16*) (ws + off_bufB);
        int*  pcol    = (int*) (ws + off_pcol);
        f16*  pval    = (f16*) (ws + off_pval);
        int*  start   = (int*) (ws + off_start);
        unsigned short* cnt16 = (unsigned short*)(ws + off_cnt16);
        int*  bcursor = (int*) (ws + off_bcursor);
        SRec* stage   = (SRec*)(ws + off_bufB);   // dead after scatter; x1 reuses

        hipMemsetAsync(bcursor, 0, (NBUCK + 4) * sizeof(int), stream);

        const int bin_blocks = (N_EDGES + BIN_CHUNK - 1) / BIN_CHUNK;      // 306
        fused_init_bin_kernel<<<bin_blocks + INIT_BLOCKS, BIN_THREADS, 0, stream>>>(
            emb_user, emb_item, x0buf,
            (const int4*)edge_row, (const int4*)edge_col, (const float4*)edge_val,
            bcursor, stage, bin_blocks);

        bucket_scan_scatter_kernel<<<NBUCK, 1024, 0, stream>>>(
            stage, bcursor, start, cnt16, pcol, pval);

        const int row_blocks = (N_NODES + 15) / 16;
        // L0: x0 -> x1   (x1 overwrites stage: stage is dead after scatter)
        spmm_csr_kernel<<<row_blocks, 256, 0, stream>>>(
            x0buf, pcol, pval, start, cnt16, x1buf, nullptr, nullptr, nullptr, 0);
        // L1: x1 -> x2
        spmm_csr_kernel<<<row_blocks, 256, 0, stream>>>(
            x1buf, pcol, pval, start, cnt16, x2buf, nullptr, nullptr, nullptr, 0);
        // L2: x2 -> epilogue: out = 0.25*(x0+x1+x2+acc), write-only out
        spmm_csr_kernel<<<row_blocks, 256, 0, stream>>>(
            x2buf, pcol, pval, start, cnt16, nullptr, x0buf, x1buf, out, 1);
    } else {
        // ---- fallback: fp32 atomic path (needs only 153.6 MB) ----
        float* fbufA = (float*)(ws + off_bufA);
        float* fbufB = (float*)(ws + off_bufB);
        init_kernel<<<el_blocks, 256, 0, stream>>>(emb_user, emb_item, fbufA, out);
        const int ew_blocks = (N_EDGES * 16 + 255) / 256;
        float* cur = fbufA;
        float* nxt = fbufB;
        for (int layer = 0; layer < 3; ++layer) {
            hipMemsetAsync(nxt, 0, node_elems * sizeof(float), stream);
            spmm_atomic_kernel<<<ew_blocks, 256, 0, stream>>>(
                cur, edge_val, edge_row, edge_col, nxt);
            addscale_kernel<<<el_blocks, 256, 0, stream>>>(
                nxt, out, (layer == 2) ? 0.25f : 1.0f);
            float* tmp = cur; cur = nxt; nxt = tmp;
        }
    }
}

// Round 13
// 524.873 us; speedup vs baseline: 1.0850x; 1.0114x over previous
//
#include <hip/hip_runtime.h>

#define N_USERS 200000
#define N_ITEMS 100000
#define N_NODES 300000
#define EMB     64
#define N_EDGES 5000000

typedef float f32x4 __attribute__((ext_vector_type(4)));
typedef _Float16 f16;
typedef f16 f16x4 __attribute__((ext_vector_type(4)));     // 8 B gather granule

// Buckets: EXACTLY 256 (one block per CU, single round — kills the 1.14-round
// tail that cost ~45-75% on both build kernels since R9). BROWS = 1172 is
// non-pow2: bucket = row / 1172 (compiler magic-mul), local = row - b*1172
// (< 1172, 11 bits). rc = local<<19 | col (col < 2^19).
#define NBUCK  256
#define BROWS  1172                                        // 256*1172 = 300032
#define CAP    20800                                       // mean 19533 (+9 sigma)
#define COLMASK 0x7FFFFu

// Bin: 256 blocks of 19532 edges (256*19532 = 5000192 >= N_EDGES).
#define BIN_CHUNK 19532
#define BIN_Q     (BIN_CHUNK / 4)                          // 4883 int4

// ---------------------------------------------------------------------------
// Fused init + bin (grid = exactly 256 blocks, 1024 threads).
//  - batch-load 5x int4 rows/cols/vals (R8/R11 latency fix)
//  - LDS bucket-sort (SoA: lrc u32 + lv f16 = 117 KB) then dense burst-out
//    (R12 write-pattern fix); stage is SoA 6 B/edge = 32 MB (was 40)
//  - x0 init grid-strided at the tail of every block (no separate blocks)
// ---------------------------------------------------------------------------
__global__ __launch_bounds__(1024) void fused_init_bin_kernel(
    const float* __restrict__ user, const float* __restrict__ item,
    f16* __restrict__ x0,
    const int4* __restrict__ row4, const int4* __restrict__ col4,
    const float4* __restrict__ val4,
    int* __restrict__ bcursor,
    unsigned int* __restrict__ stage_rc, f16* __restrict__ stage_val)
{
    __shared__ unsigned int lrc[BIN_CHUNK];    // 78,128 B
    __shared__ f16          lv[BIN_CHUNK];     // 39,064 B
    __shared__ int hist[NBUCK];                // counts -> sort cursors
    __shared__ int lstart[NBUCK + 1];          // local exclusive offsets
    __shared__ int gbase[NBUCK];               // claimed global run bases
    __shared__ int sc[NBUCK];                  // scan workspace  (~121 KB total)

    const int t = threadIdx.x;
    const int b = blockIdx.x;
    const int Q    = N_EDGES / 4;
    const int q0   = b * BIN_Q;
    int qend = q0 + BIN_Q; if (qend > Q) qend = Q;
    const int csize = (qend - q0) * 4;

    for (int k = t; k < NBUCK; k += 1024) hist[k] = 0;
    __syncthreads();

    // ---- pass A: batch row loads (5 in flight), count ----
    int4 ra[5]; bool ok[5];
    #pragma unroll
    for (int k = 0; k < 5; ++k) {
        int q = q0 + k * 1024 + t;
        ok[k] = (q < qend);
        if (ok[k]) ra[k] = row4[q];
    }
    #pragma unroll
    for (int k = 0; k < 5; ++k) {
        if (ok[k]) {
            atomicAdd(&hist[ra[k].x / BROWS], 1);
            atomicAdd(&hist[ra[k].y / BROWS], 1);
            atomicAdd(&hist[ra[k].z / BROWS], 1);
            atomicAdd(&hist[ra[k].w / BROWS], 1);
        }
    }
    __syncthreads();

    // ---- exclusive scan over 256 counts (first 256 threads) ----
    if (t < NBUCK) sc[t] = hist[t];
    __syncthreads();
    for (int ofs = 1; ofs < NBUCK; ofs <<= 1) {
        int u = 0;
        if (t < NBUCK && t >= ofs) u = sc[t - ofs];
        __syncthreads();
        if (t < NBUCK) sc[t] += u;
        __syncthreads();
    }
    if (t < NBUCK) {
        int v  = hist[t];
        int ex = sc[t] - v;
        lstart[t] = ex;
        gbase[t]  = v ? atomicAdd(&bcursor[t], v) : 0;
        hist[t]   = ex;                        // reuse as local sort cursor
    }
    if (t == 0) lstart[NBUCK] = csize;
    __syncthreads();

    // ---- pass B: batch col/val loads, sort into LDS by bucket ----
    int4 c4[5]; float4 v4[5];
    #pragma unroll
    for (int k = 0; k < 5; ++k) {
        int q = q0 + k * 1024 + t;
        if (ok[k]) { c4[k] = col4[q]; v4[k] = val4[q]; }
    }
    #pragma unroll
    for (int k = 0; k < 5; ++k) {
        if (ok[k]) {
            int   rr[4] = {ra[k].x, ra[k].y, ra[k].z, ra[k].w};
            int   cc[4] = {c4[k].x, c4[k].y, c4[k].z, c4[k].w};
            float vv[4] = {v4[k].x, v4[k].y, v4[k].z, v4[k].w};
            #pragma unroll
            for (int m = 0; m < 4; ++m) {
                int bb    = rr[m] / BROWS;
                int local = rr[m] - bb * BROWS;
                int idx   = atomicAdd(&hist[bb], 1);
                lrc[idx]  = ((unsigned)local << 19) | (unsigned)cc[m];
                lv[idx]   = (f16)vv[m];
            }
        }
    }
    __syncthreads();

    // ---- burst out: dense, line-coalesced SoA stage writes ----
    for (int i = t; i < csize; i += 1024) {
        int lo = 0, hi = NBUCK - 1;            // largest bb: lstart[bb] <= i
        while (lo < hi) {
            int mid = (lo + hi + 1) >> 1;
            if (lstart[mid] <= i) lo = mid; else hi = mid - 1;
        }
        size_t gp = (size_t)lo * CAP + gbase[lo] + (i - lstart[lo]);
        stage_rc[gp]  = lrc[i];
        stage_val[gp] = lv[i];
    }

    // ---- init tail: x0 = fp16(cat(user,item)), grid-strided ----
    const int nu4 = N_USERS * EMB / 4;
    const int nt4 = N_NODES * EMB / 4;
    for (int i = b * 1024 + t; i < nt4; i += NBUCK * 1024) {
        float4 vv = (i < nu4) ? reinterpret_cast<const float4*>(user)[i]
                              : reinterpret_cast<const float4*>(item)[i - nu4];
        f16x4 hx = {(f16)vv.x, (f16)vv.y, (f16)vv.z, (f16)vv.w};
        reinterpret_cast<f16x4*>(x0)[i] = hx;
    }
}

// ---------------------------------------------------------------------------
// Per-bucket (1172 rows, 256 blocks = 1 round): count -> scan (2/thread) ->
// LDS row-sort -> dense stream-out to BUCKET-STRIDED packed (base = b*CAP).
// LDS ~134 KB.
// ---------------------------------------------------------------------------
__global__ __launch_bounds__(1024) void bucket_scan_scatter_kernel(
    const unsigned int* __restrict__ stage_rc, const f16* __restrict__ stage_val,
    const int* __restrict__ bsize,
    int* __restrict__ start, unsigned short* __restrict__ cnt16,
    int* __restrict__ pcol, f16* __restrict__ pval)
{
    __shared__ int cur[BROWS + 2];      // 4,696 B: counts -> cursors
    __shared__ int sc[1024];
    __shared__ int lcol[CAP];           // 83,200 B
    __shared__ f16 lval[CAP];           // 41,600 B

    int b    = blockIdx.x;
    int t    = threadIdx.x;
    int row0 = b * BROWS;
    int rows = N_NODES - row0; if (rows > BROWS) rows = BROWS;

    const int size = bsize[b];
    const int base = b * CAP;
    const unsigned int* seg_rc = stage_rc  + (size_t)b * CAP;
    const f16*          seg_v  = stage_val + (size_t)b * CAP;

    for (int i = t; i < BROWS; i += 1024) cur[i] = 0;
    __syncthreads();

    // pass A: per-row counts
    for (int e = t; e < size; e += 1024)
        atomicAdd(&cur[seg_rc[e] >> 19], 1);
    __syncthreads();

    // exclusive scan over 1172 counts: 2 consecutive per thread (586 pairs)
    int a0 = 0, a1 = 0, s01 = 0;
    if (t < 586) { a0 = cur[2 * t]; a1 = cur[2 * t + 1]; s01 = a0 + a1; }
    sc[t] = s01;
    __syncthreads();
    for (int ofs = 1; ofs < 1024; ofs <<= 1) {
        int v = (t >= ofs) ? sc[t - ofs] : 0;
        __syncthreads();
        sc[t] += v;
        __syncthreads();
    }
    if (t < 586) {
        int ex = sc[t] - s01;
        cur[2 * t]     = ex;
        cur[2 * t + 1] = ex + a0;
        int r0 = 2 * t, r1 = 2 * t + 1;
        if (r0 < rows) { start[row0 + r0] = base + ex;      cnt16[row0 + r0] = (unsigned short)a0; }
        if (r1 < rows) { start[row0 + r1] = base + ex + a0; cnt16[row0 + r1] = (unsigned short)a1; }
    }
    __syncthreads();

    // pass B: row-sort into LDS (seg L2-warm from pass A)
    for (int e = t; e < size; e += 1024) {
        unsigned int rc = seg_rc[e];
        int idx = atomicAdd(&cur[rc >> 19], 1);
        lcol[idx] = (int)(rc & COLMASK);
        lval[idx] = seg_v[e];
    }
    __syncthreads();

    // stream out: dense, coalesced, payload-only
    for (int i = t; i < size; i += 1024) pcol[base + i] = lcol[i];
    for (int i = t; i < size; i += 1024) pval[base + i] = lval[i];
}

// ---------------------------------------------------------------------------
// CSR SpMM over fp16 tables (strided CSR: beg = start[g], end = beg+cnt16[g]).
// mode 0: write y only. mode 1 (layer 2): out = 0.25*(x0+x1+x2+acc).
// Established floor: compulsory L2-miss bytes (8 XCD x table + packed) at
// ~3.9 TB/s pattern rate; insensitive to MLP/nt-hints (R1/R2/R5/R6).
// ---------------------------------------------------------------------------
__global__ __launch_bounds__(256, 4) void spmm_csr_kernel(
    const f16* __restrict__ x, const int* __restrict__ pcol,
    const f16* __restrict__ pval, const int* __restrict__ start,
    const unsigned short* __restrict__ cnt16,
    f16* __restrict__ y,
    const f16* __restrict__ xa, const f16* __restrict__ xb,
    float* __restrict__ out, int mode)
{
    int g = blockIdx.x * (256 / 16) + (threadIdx.x >> 4);
    if (g >= N_NODES) return;
    const int lane16 = threadIdx.x & 15;
    const int d      = lane16 * 4;
    const int gbase  = threadIdx.x & 48;

    int beg = start[g];
    int end = beg + cnt16[g];
    float4 acc = {0.f, 0.f, 0.f, 0.f};

    for (int jb = beg; jb < end; jb += 16) {
        int   mycol = 0; float myval = 0.f;
        if (jb + lane16 < end) {
            mycol = pcol[jb + lane16];
            myval = (float)pval[jb + lane16];
        }

        int   cols[16];
        float vals[16];
        #pragma unroll
        for (int k = 0; k < 16; ++k) {
            cols[k] = __shfl(mycol, gbase + k, 64);
            vals[k] = __shfl(myval, gbase + k, 64);
        }

        f16x4 xv[16];
        #pragma unroll
        for (int k = 0; k < 16; ++k) {
            xv[k] = *reinterpret_cast<const f16x4*>(
                x + (size_t)cols[k] * EMB + d);
        }

        #pragma unroll
        for (int k = 0; k < 16; ++k) {
            acc.x += vals[k] * (float)xv[k].x;
            acc.y += vals[k] * (float)xv[k].y;
            acc.z += vals[k] * (float)xv[k].z;
            acc.w += vals[k] * (float)xv[k].w;
        }
    }

    const size_t rofs = (size_t)g * EMB + d;
    if (mode == 0) {
        f16x4 hy = {(f16)acc.x, (f16)acc.y, (f16)acc.z, (f16)acc.w};
        *reinterpret_cast<f16x4*>(y + rofs) = hy;
    } else {
        f16x4 v0 = *reinterpret_cast<const f16x4*>(xa + rofs);
        f16x4 v1 = *reinterpret_cast<const f16x4*>(xb + rofs);
        f16x4 v2 = *reinterpret_cast<const f16x4*>(x  + rofs);
        f32x4 o;
        o.x = 0.25f * ((float)v0.x + (float)v1.x + (float)v2.x + acc.x);
        o.y = 0.25f * ((float)v0.y + (float)v1.y + (float)v2.y + acc.y);
        o.z = 0.25f * ((float)v0.z + (float)v1.z + (float)v2.z + acc.z);
        o.w = 0.25f * ((float)v0.w + (float)v1.w + (float)v2.w + acc.w);
        __builtin_nontemporal_store(o, reinterpret_cast<f32x4*>(out + rofs));
    }
}

// ---------------------------------------------------------------------------
// Fallback path (ws too small for CSR): unchanged fp32 atomic path.
// ---------------------------------------------------------------------------
__global__ __launch_bounds__(256) void init_kernel(
    const float* __restrict__ user, const float* __restrict__ item,
    float* __restrict__ x, float* __restrict__ out)
{
    const int nu4 = N_USERS * EMB / 4;
    const int nt4 = N_NODES * EMB / 4;
    int i = blockIdx.x * blockDim.x + threadIdx.x;
    if (i >= nt4) return;
    float4 v = (i < nu4) ? reinterpret_cast<const float4*>(user)[i]
                         : reinterpret_cast<const float4*>(item)[i - nu4];
    reinterpret_cast<float4*>(x)[i]   = v;
    reinterpret_cast<float4*>(out)[i] = v;
}

__global__ __launch_bounds__(256) void spmm_atomic_kernel(
    const float* __restrict__ x, const float* __restrict__ val,
    const int* __restrict__ row, const int* __restrict__ col,
    float* __restrict__ y)
{
    int t = blockIdx.x * blockDim.x + threadIdx.x;
    int e = t >> 4;
    if (e >= N_EDGES) return;
    int d = (t & 15) * 4;
    int   r = row[e];
    int   c = col[e];
    float v = val[e];
    float4 xv = *reinterpret_cast<const float4*>(x + c * EMB + d);
    float* yp = y + r * EMB + d;
    unsafeAtomicAdd(yp + 0, v * xv.x);
    unsafeAtomicAdd(yp + 1, v * xv.y);
    unsafeAtomicAdd(yp + 2, v * xv.z);
    unsafeAtomicAdd(yp + 3, v * xv.w);
}

__global__ __launch_bounds__(256) void addscale_kernel(
    const float* __restrict__ xl, float* __restrict__ out, float scale)
{
    const int nt4 = N_NODES * EMB / 4;
    int i = blockIdx.x * blockDim.x + threadIdx.x;
    if (i >= nt4) return;
    float4 a = reinterpret_cast<float4*>(out)[i];
    float4 b = reinterpret_cast<const float4*>(xl)[i];
    a.x = (a.x + b.x) * scale;
    a.y = (a.y + b.y) * scale;
    a.z = (a.z + b.z) * scale;
    a.w = (a.w + b.w) * scale;
    reinterpret_cast<float4*>(out)[i] = a;
}

extern "C" void kernel_launch(void* const* d_in, const int* in_sizes, int n_in,
                              void* d_out, int out_size, void* d_ws, size_t ws_size,
                              hipStream_t stream) {
    const float* emb_user = (const float*)d_in[0];
    const float* emb_item = (const float*)d_in[1];
    const float* edge_val = (const float*)d_in[2];
    const int*   edge_row = (const int*)d_in[3];
    const int*   edge_col = (const int*)d_in[4];
    float* out = (float*)d_out;

    const size_t node_elems = (size_t)N_NODES * EMB;        // 19.2M elems
    const size_t SEG        = (size_t)NBUCK * CAP;          // 5,324,800 slots
    char* ws = (char*)d_ws;

    // workspace layout:
    //  region A (76.8 MB): x0 fp16 [0,38.4) | x2 fp16 [38.4,76.8)
    //  region B (76.8 MB): stage SoA (rc 21.3 + val 10.65 MB) during build;
    //                      x1 fp16 [0,38.4) after (stage dead post-scatter)
    //  packed (bucket-strided): pcol 21.3 MB + pval 10.65 MB
    const size_t off_bufA    = 0;
    const size_t off_bufB    = off_bufA + node_elems * sizeof(float);      // 76.8 MB
    const size_t off_pcol    = off_bufB + node_elems * sizeof(float);      // 153.6 MB
    const size_t off_pval    = off_pcol + SEG * sizeof(int);
    const size_t off_start   = off_pval + SEG * sizeof(f16);
    const size_t off_cnt16   = off_start + (N_NODES + 4) * sizeof(int);
    const size_t off_bcursor = off_cnt16 + (N_NODES + 4) * sizeof(unsigned short);
    const size_t needed      = off_bcursor + (NBUCK + 4) * sizeof(int);    // ~187.4 MB

    const int nt4       = N_NODES * EMB / 4;
    const int el_blocks = (nt4 + 255) / 256;

    // stage SoA (6 B/slot) must fit in region B
    static_assert(SEG * 6 <= (size_t)N_NODES * EMB * sizeof(float),
                  "stage must fit in bufB region");
    static_assert((size_t)NBUCK * BROWS >= N_NODES, "buckets must cover rows");

    if (ws_size >= needed) {
        // ---- CSR path (fp16 tables, strided SoA packed, deferred combine) ----
        f16*  x0buf   = (f16*) (ws + off_bufA);
        f16*  x2buf   = (f16*) (ws + off_bufA) + node_elems;   // +38.4 MB
        f16*  x1buf   = (f16*) (ws + off_bufB);
        unsigned int* stage_rc  = (unsigned int*)(ws + off_bufB);
        f16*          stage_val = (f16*)(ws + off_bufB + SEG * sizeof(int));
        int*  pcol    = (int*) (ws + off_pcol);
        f16*  pval    = (f16*) (ws + off_pval);
        int*  start   = (int*) (ws + off_start);
        unsigned short* cnt16 = (unsigned short*)(ws + off_cnt16);
        int*  bcursor = (int*) (ws + off_bcursor);

        hipMemsetAsync(bcursor, 0, (NBUCK + 4) * sizeof(int), stream);

        fused_init_bin_kernel<<<NBUCK, 1024, 0, stream>>>(
            emb_user, emb_item, x0buf,
            (const int4*)edge_row, (const int4*)edge_col, (const float4*)edge_val,
            bcursor, stage_rc, stage_val);

        bucket_scan_scatter_kernel<<<NBUCK, 1024, 0, stream>>>(
            stage_rc, stage_val, bcursor, start, cnt16, pcol, pval);

        const int row_blocks = (N_NODES + 15) / 16;
        // L0: x0 -> x1   (x1 overwrites stage: stage is dead after scatter)
        spmm_csr_kernel<<<row_blocks, 256, 0, stream>>>(
            x0buf, pcol, pval, start, cnt16, x1buf, nullptr, nullptr, nullptr, 0);
        // L1: x1 -> x2
        spmm_csr_kernel<<<row_blocks, 256, 0, stream>>>(
            x1buf, pcol, pval, start, cnt16, x2buf, nullptr, nullptr, nullptr, 0);
        // L2: x2 -> epilogue: out = 0.25*(x0+x1+x2+acc), write-only out
        spmm_csr_kernel<<<row_blocks, 256, 0, stream>>>(
            x2buf, pcol, pval, start, cnt16, nullptr, x0buf, x1buf, out, 1);
    } else {
        // ---- fallback: fp32 atomic path (needs only 153.6 MB) ----
        float* fbufA = (float*)(ws + off_bufA);
        float* fbufB = (float*)(ws + off_bufB);
        init_kernel<<<el_blocks, 256, 0, stream>>>(emb_user, emb_item, fbufA, out);
        const int ew_blocks = (N_EDGES * 16 + 255) / 256;
        float* cur = fbufA;
        float* nxt = fbufB;
        for (int layer = 0; layer < 3; ++layer) {
            hipMemsetAsync(nxt, 0, node_elems * sizeof(float), stream);
            spmm_atomic_kernel<<<ew_blocks, 256, 0, stream>>>(
                cur, edge_val, edge_row, edge_col, nxt);
            addscale_kernel<<<el_blocks, 256, 0, stream>>>(
                nxt, out, (layer == 2) ? 0.25f : 1.0f);
            float* tmp = cur; cur = nxt; nxt = tmp;
        }
    }
}